// Round 7
// baseline (162.235 us; speedup 1.0000x reference)
//
#include <hip/hip_runtime.h>
#include <hip/hip_bf16.h>

#define BB 8
#define CIN 512
#define COUT 512
#define HH 64
#define WW 64

#define AFF_SCALE 0.044194173824159216f     // 1/sqrt(512)
#define CONV_SCALE 0.014731391274719736f    // 1/sqrt(4608)
#define CONV_SCALE2 (1.0f/4608.0f)

typedef short s16x8 __attribute__((ext_vector_type(8)));
typedef float f32x4 __attribute__((ext_vector_type(4)));
typedef float f32x16 __attribute__((ext_vector_type(16)));

__device__ __forceinline__ unsigned short f2bf(float f) {
  __hip_bfloat16 h = __float2bfloat16(f);
  return *reinterpret_cast<unsigned short*>(&h);
}

// zero-register global->LDS DMA, 16B per lane; LDS dest = uniform base + lane*16
__device__ __forceinline__ void gload_lds16(const void* g, void* l) {
  __builtin_amdgcn_global_load_lds(
      (const __attribute__((address_space(1))) unsigned int*)g,
      (__attribute__((address_space(3))) unsigned int*)l, 16, 0, 0);
}

// ---------------------------------------------------------------------------
// smod[b*CIN+ic] = dot(style[b,:], w_affine[ic,:]) * AFF_SCALE + ba[ic]
// ---------------------------------------------------------------------------
__global__ __launch_bounds__(256) void affine_kernel(
    const float* __restrict__ style, const float* __restrict__ wa,
    const float* __restrict__ ba, float* __restrict__ smod) {
  int wid  = (blockIdx.x << 2) + (threadIdx.x >> 6);
  int lane = threadIdx.x & 63;
  int b  = wid >> 9;
  int ic = wid & 511;
  const float* s = style + b * CIN;
  const float* w = wa + (size_t)ic * CIN;
  float sum = 0.f;
#pragma unroll
  for (int k = 0; k < CIN / 64; ++k) sum += s[lane + 64 * k] * w[lane + 64 * k];
#pragma unroll
  for (int off = 32; off; off >>= 1) sum += __shfl_down(sum, off, 64);
  if (lane == 0) smod[wid] = sum * AFF_SCALE + ba[ic];
}

// ---------------------------------------------------------------------------
// wsq[oc*CIN+ic] = sum_k w_conv[oc,ic,k]^2
// ---------------------------------------------------------------------------
__global__ __launch_bounds__(256) void wsq_kernel(
    const float* __restrict__ wc, float* __restrict__ wsq) {
  int i = blockIdx.x * 256 + threadIdx.x;
  const float* p = wc + (size_t)i * 9;
  float s = 0.f;
#pragma unroll
  for (int k = 0; k < 9; ++k) { float v = p[k]; s += v * v; }
  wsq[i] = s;
}

// ---------------------------------------------------------------------------
// demod[b*COUT+oc] = rsqrt(CS2 * sum_ic smod^2 * wsq + eps) * CS
// ---------------------------------------------------------------------------
__global__ __launch_bounds__(256) void demod_kernel(
    const float* __restrict__ smod, const float* __restrict__ wsq,
    float* __restrict__ demod) {
  int wid  = (blockIdx.x << 2) + (threadIdx.x >> 6);
  int lane = threadIdx.x & 63;
  int b  = wid >> 9;
  int oc = wid & 511;
  const float* s = smod + b * CIN;
  const float* w = wsq + (size_t)oc * CIN;
  float sum = 0.f;
#pragma unroll
  for (int k = 0; k < CIN / 64; ++k) {
    float sv = s[lane + 64 * k];
    sum += sv * sv * w[lane + 64 * k];
  }
#pragma unroll
  for (int off = 32; off; off >>= 1) sum += __shfl_down(sum, off, 64);
  if (lane == 0) demod[wid] = rsqrtf(sum * CONV_SCALE2 + 1e-8f) * CONV_SCALE;
}

// ---------------------------------------------------------------------------
// premod: xt[b][g][y][x][ic32] bf16 = input[b][ic][y][x] * smod[b][ic]
// ---------------------------------------------------------------------------
__global__ __launch_bounds__(256) void premod_kernel(
    const float* __restrict__ xin, const float* __restrict__ smod,
    ushort* __restrict__ xt) {
  int n = blockIdx.x * 256 + threadIdx.x;   // < 2,097,152
  int kg = n & 3;
  int x  = (n >> 2) & 63;
  int y  = (n >> 8) & 63;
  int g  = (n >> 14) & 15;
  int b  = n >> 18;
  int ic0 = g * 32 + kg * 8;
  const float* sp = smod + b * CIN + ic0;
  const float* xp = xin + (((size_t)b * CIN + ic0) * HH + y) * WW + x;
  s16x8 o;
#pragma unroll
  for (int j = 0; j < 8; ++j) {
    float v = xp[(size_t)j * HH * WW] * sp[j];
    o[j] = (short)f2bf(v);
  }
  *(s16x8*)(xt + (size_t)n * 8) = o;
}

// ---------------------------------------------------------------------------
// wpack (R7, 32x32x16 A-fragment order):
//   wfrag[widx][mf][ks][l][8], element = wc[oc = mf*32 + (l&31)]
//                                          [ic = g*32 + ks*16 + 8*(l>>5) + j]
//                                          [kh][kw],  widx = g*9 + tap
// ---------------------------------------------------------------------------
__global__ __launch_bounds__(256) void wpack_kernel(
    const float* __restrict__ wc, ushort* __restrict__ wfrag) {
  int n = blockIdx.x * 256 + threadIdx.x;   // < 294,912 = 144*16*2*64
  int l    = n & 63;
  int ks   = (n >> 6) & 1;
  int mf   = (n >> 7) & 15;
  int widx = n >> 11;           // 0..143
  int g = widx / 9, tap = widx % 9;
  int kh = tap / 3, kw = tap - kh * 3;
  int oc  = mf * 32 + (l & 31);
  int ic0 = g * 32 + ks * 16 + 8 * (l >> 5);
  s16x8 o;
#pragma unroll
  for (int j = 0; j < 8; ++j) {
    float v = wc[((size_t)oc * CIN + ic0 + j) * 9 + kh * 3 + kw];
    o[j] = (short)f2bf(v);
  }
  *(s16x8*)(wfrag + (size_t)n * 8) = o;
}

// ---------------------------------------------------------------------------
// conv_mfma (R7): same structure as R6 (xs DMA staging + XOR swizzle, 3-slot
// half-cluster weight rotation, 16 barriers) but MFMA 32x32x16 (2382 TF
// ceiling, half the instruction count) and counted vmcnt(8) at the g-barrier
// (tap-8's two weight half-prefetches stay in flight; in-order retirement
// guarantees the 6 staging DMAs issued at tap 6 are drained).
// Wave tile 128oc x 64px = 4(m) x 2(n) frags x 2 k-slices; acc 128 AGPR.
// ---------------------------------------------------------------------------
#define XS_ROW 4224                 // 66 cols * 4 kg * 16 B
#define XS_BUF (6 * XS_ROW)         // 25344 B per buffer

__global__ __launch_bounds__(256, 2) void conv_mfma(
    const ushort* __restrict__ xt,     // [8][16][64][64][32] bf16
    const ushort* __restrict__ wfrag,  // [144][16][2][64][8] bf16
    const float* __restrict__ demod,
    float* __restrict__ out) {
  __shared__ char lds[2 * XS_BUF];    // 50688 B -> 2 blocks/CU

  int tid = threadIdx.x;
  int l = tid & 63, w = tid >> 6;
  int bid = blockIdx.x;
  int ocb = bid & 3;
  int b   = (bid >> 2) & 7;
  int yt  = bid >> 5;           // 0..15
  int y0  = yt * 4;

  f32x16 acc[4][2];
#pragma unroll
  for (int i = 0; i < 4; ++i)
#pragma unroll
    for (int j = 0; j < 2; ++j)
#pragma unroll
      for (int e = 0; e < 16; ++e) acc[i][j][e] = 0.f;

  // zero always-zero halo COLUMNS (col 0 -> chunks 0..3, col 65 -> 260..263)
  if (tid < 96) {
    int buf = tid & 1, side = (tid >> 1) & 1, kgz = (tid >> 2) & 3, r = tid >> 4;
    int chunk = side ? (260 + kgz) : kgz;
    *(int4*)(lds + buf * XS_BUF + r * XS_ROW + chunk * 16) = int4{0, 0, 0, 0};
  }
  // zero y-halo ROWS for edge blocks (never re-staged -> stay zero)
  if (y0 == 0) {
    for (int i = tid; i < 512; i += 256) {
      int buf = i & 1, chunk = 4 + (i >> 1);
      *(int4*)(lds + buf * XS_BUF + chunk * 16) = int4{0, 0, 0, 0};
    }
  }
  if (y0 == 60) {
    for (int i = tid; i < 512; i += 256) {
      int buf = i & 1, chunk = 4 + (i >> 1);
      *(int4*)(lds + buf * XS_BUF + 5 * XS_ROW + chunk * 16) = int4{0, 0, 0, 0};
    }
  }

  // B-fragment read offsets (swizzled): col = fn*32 + (l&31) + dxi,
  // kg = (l>>5) + 2*ks;  addr = (col*4 + (kg ^ ((col>>1)&3))) * 16
  int boffs[2][3][2];
  {
    int lm = l & 31, kh2 = l >> 5;
#pragma unroll
    for (int fn = 0; fn < 2; ++fn)
#pragma unroll
      for (int dxi = 0; dxi < 3; ++dxi)
#pragma unroll
        for (int ks = 0; ks < 2; ++ks) {
          int col = fn * 32 + lm + dxi;                    // 0..65
          int kg  = kh2 + 2 * ks;
          boffs[fn][dxi][ks] = (col * 4 + (kg ^ ((col >> 1) & 3))) * 16;
        }
  }

  // staging: wave w covers quarter q=w of each row; per-lane PRE-SWIZZLED
  // global source offset within a 4KB xt row
  int col_s = 1 + w * 16 + (l >> 2);
  int srcoff = (col_s - 1) * 64 + ((l & 3) ^ ((col_s >> 1) & 3)) * 16;
  int lds_woff = 64 + w * 1024;   // + r*XS_ROW (+buf*XS_BUF)

  const char* xtb = (const char*)xt;
  // per-lane weight base: frag (mf=ocb*4+q, ks) of kstep k at
  //   wl + k*32768 + q*2048 + ks*1024
  const char* wl = (const char*)wfrag + (size_t)ocb * 8192 + (size_t)l * 16;

  // 3-slot half-cluster rotation: slot s holds half H (=2*kstep+ks), H%3==s.
  s16x8 wH[3][4];
#pragma unroll
  for (int q = 0; q < 4; ++q) wH[0][q] = *(const s16x8*)(wl + q * 2048);          // H=0
#pragma unroll
  for (int q = 0; q < 4; ++q) wH[1][q] = *(const s16x8*)(wl + q * 2048 + 1024);   // H=1

  // prologue: stage g=0 into buffer 0
  {
    size_t gbase = (size_t)(b * 16) * 262144;             // (b,g) plane, bytes
#pragma unroll
    for (int r = 0; r < 6; ++r) {
      int gy = y0 - 1 + r;
      if (gy >= 0 && gy < HH)
        gload_lds16(xtb + gbase + (size_t)gy * 4096 + srcoff,
                    lds + r * XS_ROW + lds_woff);
    }
  }
  __syncthreads();

  for (int g2 = 0; g2 < 8; ++g2) {
    const char* wg = wl + (size_t)g2 * 589824;   // base of kstep 18*g2
#pragma unroll
    for (int gg = 0; gg < 2; ++gg) {
      char* xs_r = lds + gg * XS_BUF;
      char* xs_w = lds + (gg ^ 1) * XS_BUF;
#pragma unroll
      for (int tap = 0; tap < 9; ++tap) {
        const int X0 = 2 * (gg * 9 + tap);       // even phase id (compile-time)

        // stage next g's xs early (tap 6) -> ~2.5 taps of latency cover
        if (tap == 6 && (gg == 0 || g2 < 7)) {
          __builtin_amdgcn_sched_barrier(0);
          size_t gbase = (size_t)(b * 16 + g2 * 2 + gg + 1) * 262144;
#pragma unroll
          for (int r = 0; r < 6; ++r) {
            int gy = y0 - 1 + r;
            if (gy >= 0 && gy < HH)
              gload_lds16(xtb + gbase + (size_t)gy * 4096 + srcoff,
                          xs_w + r * XS_ROW + lds_woff);
          }
          __builtin_amdgcn_sched_barrier(0);
        }

        // B fragments for this tap: bfr[fn][ks]
        const int dy = tap / 3 - 1, dxi = tap % 3;
        const int rb = w + 1 + dy;
        s16x8 bfr[2][2];
#pragma unroll
        for (int fn = 0; fn < 2; ++fn)
#pragma unroll
          for (int ks = 0; ks < 2; ++ks)
            bfr[fn][ks] = *(const s16x8*)(xs_r + rb * XS_ROW + boffs[fn][dxi][ks]);

        // ---- phase h=0: k-slice 0, prefetch half X0+2 ----
        {
          const int u = X0 % 3, v = (X0 + 2) % 3;
          const char* wp = wg + (size_t)((X0 + 2) >> 1) * 32768 + ((X0 + 2) & 1) * 1024;
#pragma unroll
          for (int q = 0; q < 4; ++q) wH[v][q] = *(const s16x8*)(wp + q * 2048);
          __builtin_amdgcn_s_setprio(1);
#pragma unroll
          for (int q = 0; q < 4; ++q)
#pragma unroll
            for (int fn = 0; fn < 2; ++fn)
              acc[q][fn] = __builtin_amdgcn_mfma_f32_32x32x16_bf16(wH[u][q], bfr[fn][0], acc[q][fn], 0, 0, 0);
          __builtin_amdgcn_s_setprio(0);
        }
        // ---- phase h=1: k-slice 1, prefetch half X0+3 ----
        {
          const int u = (X0 + 1) % 3, v = (X0 + 3) % 3;
          const char* wp = wg + (size_t)((X0 + 3) >> 1) * 32768 + ((X0 + 3) & 1) * 1024;
#pragma unroll
          for (int q = 0; q < 4; ++q) wH[v][q] = *(const s16x8*)(wp + q * 2048);
          __builtin_amdgcn_s_setprio(1);
#pragma unroll
          for (int q = 0; q < 4; ++q)
#pragma unroll
            for (int fn = 0; fn < 2; ++fn)
              acc[q][fn] = __builtin_amdgcn_mfma_f32_32x32x16_bf16(wH[u][q], bfr[fn][1], acc[q][fn], 0, 0, 0);
          __builtin_amdgcn_s_setprio(0);
        }

        if (tap == 8 && (gg == 0 || g2 < 7)) {
          // counted drain: allow tap-8's 8 weight loads to stay in flight;
          // in-order retirement => the 6 staging DMAs (tap 6) are complete
          __builtin_amdgcn_sched_barrier(0);
          asm volatile("s_waitcnt vmcnt(8)" ::: "memory");
          __builtin_amdgcn_sched_barrier(0);
          __builtin_amdgcn_s_barrier();
          __builtin_amdgcn_sched_barrier(0);
        }
      }
    }
  }

  // ---- epilogue: demod scale + store ----
  // C/D 32x32: col = l&31, row = (reg&3) + 8*(reg>>2) + 4*(l>>5)
  int gy = y0 + w;
  int colbase = l & 31;
  int rowadd = 4 * (l >> 5);
#pragma unroll
  for (int q = 0; q < 4; ++q) {
#pragma unroll
    for (int reg = 0; reg < 16; ++reg) {
      int row = (reg & 3) + 8 * (reg >> 2) + rowadd;
      int oc = ocb * 128 + q * 32 + row;
      float dm = demod[b * COUT + oc];
      size_t obase = ((size_t)(b * COUT + oc)) * 4096 + gy * 64;
      out[obase + colbase]      = acc[q][0][reg] * dm;
      out[obase + 32 + colbase] = acc[q][1][reg] * dm;
    }
  }
}

// ---------------------------------------------------------------------------
extern "C" void kernel_launch(void* const* d_in, const int* in_sizes, int n_in,
                              void* d_out, int out_size, void* d_ws, size_t ws_size,
                              hipStream_t stream) {
  const float* input = (const float*)d_in[0];  // [8,512,64,64]
  const float* style = (const float*)d_in[1];  // [8,512]
  const float* wa    = (const float*)d_in[2];  // [512,512]
  const float* ba    = (const float*)d_in[3];  // [1,512]
  const float* wconv = (const float*)d_in[4];  // [512,512,3,3]
  float* out = (float*)d_out;

  float* smod  = (float*)d_ws;                    // 4096 f
  float* demod = smod + BB * CIN;                 // 4096 f
  float* wsq   = demod + BB * COUT;               // 262144 f
  ushort* wfrag = (ushort*)(wsq + (size_t)COUT * CIN);   // 2,359,296 us (4.5 MB)
  ushort* xt    = wfrag + (size_t)16 * 9 * 32 * 64 * 8;  // 16,777,216 us (32 MB)

  affine_kernel<<<BB * CIN / 4, 256, 0, stream>>>(style, wa, ba, smod);
  wsq_kernel<<<COUT * CIN / 256, 256, 0, stream>>>(wconv, wsq);
  demod_kernel<<<BB * COUT / 4, 256, 0, stream>>>(smod, wsq, demod);
  wpack_kernel<<<16 * 9 * 32 * 64 / 256, 256, 0, stream>>>(wconv, wfrag);
  premod_kernel<<<BB * 16 * 64 * 64 * 4 / 256, 256, 0, stream>>>(input, smod, xt);
  conv_mfma<<<BB * 4 * 16, 256, 0, stream>>>(xt, wfrag, demod, out);
}

// Round 8
// 156.198 us; speedup vs baseline: 1.0386x; 1.0386x over previous
//
#include <hip/hip_runtime.h>
#include <hip/hip_bf16.h>

#define BB 8
#define CIN 512
#define COUT 512
#define HH 64
#define WW 64

#define AFF_SCALE 0.044194173824159216f     // 1/sqrt(512)
#define CONV_SCALE 0.014731391274719736f    // 1/sqrt(4608)
#define CONV_SCALE2 (1.0f/4608.0f)

typedef short s16x8 __attribute__((ext_vector_type(8)));
typedef float f32x16 __attribute__((ext_vector_type(16)));

__device__ __forceinline__ unsigned short f2bf(float f) {
  __hip_bfloat16 h = __float2bfloat16(f);
  return *reinterpret_cast<unsigned short*>(&h);
}

// zero-register global->LDS DMA, 16B per lane; LDS dest = uniform base + lane*16
__device__ __forceinline__ void gload_lds16(const void* g, void* l) {
  __builtin_amdgcn_global_load_lds(
      (const __attribute__((address_space(1))) unsigned int*)g,
      (__attribute__((address_space(3))) unsigned int*)l, 16, 0, 0);
}

// ---------------------------------------------------------------------------
// smod[b*CIN+ic] = dot(style[b,:], w_affine[ic,:]) * AFF_SCALE + ba[ic]
// ---------------------------------------------------------------------------
__global__ __launch_bounds__(256) void affine_kernel(
    const float* __restrict__ style, const float* __restrict__ wa,
    const float* __restrict__ ba, float* __restrict__ smod) {
  int wid  = (blockIdx.x << 2) + (threadIdx.x >> 6);
  int lane = threadIdx.x & 63;
  int b  = wid >> 9;
  int ic = wid & 511;
  const float* s = style + b * CIN;
  const float* w = wa + (size_t)ic * CIN;
  float sum = 0.f;
#pragma unroll
  for (int k = 0; k < CIN / 64; ++k) sum += s[lane + 64 * k] * w[lane + 64 * k];
#pragma unroll
  for (int off = 32; off; off >>= 1) sum += __shfl_down(sum, off, 64);
  if (lane == 0) smod[wid] = sum * AFF_SCALE + ba[ic];
}

// ---------------------------------------------------------------------------
// wsq[oc*CIN+ic] = sum_k w_conv[oc,ic,k]^2
// ---------------------------------------------------------------------------
__global__ __launch_bounds__(256) void wsq_kernel(
    const float* __restrict__ wc, float* __restrict__ wsq) {
  int i = blockIdx.x * 256 + threadIdx.x;
  const float* p = wc + (size_t)i * 9;
  float s = 0.f;
#pragma unroll
  for (int k = 0; k < 9; ++k) { float v = p[k]; s += v * v; }
  wsq[i] = s;
}

// ---------------------------------------------------------------------------
// demod[b*COUT+oc] = rsqrt(CS2 * sum_ic smod^2 * wsq + eps) * CS
// ---------------------------------------------------------------------------
__global__ __launch_bounds__(256) void demod_kernel(
    const float* __restrict__ smod, const float* __restrict__ wsq,
    float* __restrict__ demod) {
  int wid  = (blockIdx.x << 2) + (threadIdx.x >> 6);
  int lane = threadIdx.x & 63;
  int b  = wid >> 9;
  int oc = wid & 511;
  const float* s = smod + b * CIN;
  const float* w = wsq + (size_t)oc * CIN;
  float sum = 0.f;
#pragma unroll
  for (int k = 0; k < CIN / 64; ++k) {
    float sv = s[lane + 64 * k];
    sum += sv * sv * w[lane + 64 * k];
  }
#pragma unroll
  for (int off = 32; off; off >>= 1) sum += __shfl_down(sum, off, 64);
  if (lane == 0) demod[wid] = rsqrtf(sum * CONV_SCALE2 + 1e-8f) * CONV_SCALE;
}

// ---------------------------------------------------------------------------
// premod: xt[b][g][y][x][ic32] bf16 = input[b][ic][y][x] * smod[b][ic]
// ---------------------------------------------------------------------------
__global__ __launch_bounds__(256) void premod_kernel(
    const float* __restrict__ xin, const float* __restrict__ smod,
    ushort* __restrict__ xt) {
  int n = blockIdx.x * 256 + threadIdx.x;   // < 2,097,152
  int kg = n & 3;
  int x  = (n >> 2) & 63;
  int y  = (n >> 8) & 63;
  int g  = (n >> 14) & 15;
  int b  = n >> 18;
  int ic0 = g * 32 + kg * 8;
  const float* sp = smod + b * CIN + ic0;
  const float* xp = xin + (((size_t)b * CIN + ic0) * HH + y) * WW + x;
  s16x8 o;
#pragma unroll
  for (int j = 0; j < 8; ++j) {
    float v = xp[(size_t)j * HH * WW] * sp[j];
    o[j] = (short)f2bf(v);
  }
  *(s16x8*)(xt + (size_t)n * 8) = o;
}

// ---------------------------------------------------------------------------
// wpack (32x32x16 A-fragment order):
//   wfrag[widx][mf][ks][l][8], element = wc[oc = mf*32 + (l&31)]
//                                          [ic = g*32 + ks*16 + 8*(l>>5) + j]
//                                          [kh][kw],  widx = g*9 + tap
// ---------------------------------------------------------------------------
__global__ __launch_bounds__(256) void wpack_kernel(
    const float* __restrict__ wc, ushort* __restrict__ wfrag) {
  int n = blockIdx.x * 256 + threadIdx.x;   // < 294,912 = 144*16*2*64
  int l    = n & 63;
  int ks   = (n >> 6) & 1;
  int mf   = (n >> 7) & 15;
  int widx = n >> 11;           // 0..143
  int g = widx / 9, tap = widx % 9;
  int kh = tap / 3, kw = tap - kh * 3;
  int oc  = mf * 32 + (l & 31);
  int ic0 = g * 32 + ks * 16 + 8 * (l >> 5);
  s16x8 o;
#pragma unroll
  for (int j = 0; j < 8; ++j) {
    float v = wc[((size_t)oc * CIN + ic0 + j) * 9 + kh * 3 + kw];
    o[j] = (short)f2bf(v);
  }
  *(s16x8*)(wfrag + (size_t)n * 8) = o;
}

// ---------------------------------------------------------------------------
// conv_mfma (R8): 32x32x16 MFMA; wave tile re-split 2m x 4n (64oc x 2rows x
// 64px) so per-wave weight traffic halves (4KB/kstep -> 32KB/kstep/CU, under
// the 1033-cyc MFMA floor). bfr register double-buffering: next tap's ks0
// fragments prefetched under this tap's h1 MFMAs; ks1 fragments read under
// h0 MFMAs -> LDS latency never exposed (except tap 0, 1/9 amortized).
// Weights global->VGPR 3-slot rotation wH[3][2] (24 VGPR), 2 halves ahead.
// xs staging/swizzle/zeroing byte-identical to R5-R7.
// ---------------------------------------------------------------------------
#define XS_ROW 4224                 // 66 cols * 4 kg * 16 B
#define XS_BUF (6 * XS_ROW)         // 25344 B per buffer

__global__ __launch_bounds__(256, 2) void conv_mfma(
    const ushort* __restrict__ xt,     // [8][16][64][64][32] bf16
    const ushort* __restrict__ wfrag,  // [144][16][2][64][8] bf16
    const float* __restrict__ demod,
    float* __restrict__ out) {
  __shared__ char lds[2 * XS_BUF];    // 50688 B -> 2 blocks/CU

  int tid = threadIdx.x;
  int l = tid & 63, w = tid >> 6;
  int wm = w >> 1, wr = w & 1;        // oc-half, row-pair
  int bid = blockIdx.x;
  int ocb = bid & 3;
  int b   = (bid >> 2) & 7;
  int yt  = bid >> 5;           // 0..15
  int y0  = yt * 4;

  f32x16 acc[2][4];
#pragma unroll
  for (int i = 0; i < 2; ++i)
#pragma unroll
    for (int j = 0; j < 4; ++j)
#pragma unroll
      for (int e = 0; e < 16; ++e) acc[i][j][e] = 0.f;

  // zero always-zero halo COLUMNS (col 0 -> chunks 0..3, col 65 -> 260..263)
  if (tid < 96) {
    int buf = tid & 1, side = (tid >> 1) & 1, kgz = (tid >> 2) & 3, r = tid >> 4;
    int chunk = side ? (260 + kgz) : kgz;
    *(int4*)(lds + buf * XS_BUF + r * XS_ROW + chunk * 16) = int4{0, 0, 0, 0};
  }
  // zero y-halo ROWS for edge blocks (never re-staged -> stay zero)
  if (y0 == 0) {
    for (int i = tid; i < 512; i += 256) {
      int buf = i & 1, chunk = 4 + (i >> 1);
      *(int4*)(lds + buf * XS_BUF + chunk * 16) = int4{0, 0, 0, 0};
    }
  }
  if (y0 == 60) {
    for (int i = tid; i < 512; i += 256) {
      int buf = i & 1, chunk = 4 + (i >> 1);
      *(int4*)(lds + buf * XS_BUF + 5 * XS_ROW + chunk * 16) = int4{0, 0, 0, 0};
    }
  }

  // B-fragment read offsets (swizzled): col = ph*32 + (l&31) + dxi,
  // kg = (l>>5) + 2*ks;  addr = (col*4 + (kg ^ ((col>>1)&3))) * 16
  int boffs[2][3][2];
  {
    int lm = l & 31, kh2 = l >> 5;
#pragma unroll
    for (int ph = 0; ph < 2; ++ph)
#pragma unroll
      for (int dxi = 0; dxi < 3; ++dxi)
#pragma unroll
        for (int ks = 0; ks < 2; ++ks) {
          int col = ph * 32 + lm + dxi;                    // 0..65
          int kg  = kh2 + 2 * ks;
          boffs[ph][dxi][ks] = (col * 4 + (kg ^ ((col >> 1) & 3))) * 16;
        }
  }

  // staging: wave w covers quarter q=w of each row; per-lane PRE-SWIZZLED
  // global source offset within a 4KB xt row
  int col_s = 1 + w * 16 + (l >> 2);
  int srcoff = (col_s - 1) * 64 + ((l & 3) ^ ((col_s >> 1) & 3)) * 16;
  int lds_woff = 64 + w * 1024;   // + r*XS_ROW (+buf*XS_BUF)

  const char* xtb = (const char*)xt;
  // per-lane weight base for this wave's 2 m-frags:
  //   frag q (0..1), ks at  wl + kstep*32768 + q*2048 + ks*1024
  const char* wl = (const char*)wfrag + (size_t)(ocb * 4 + wm * 2) * 2048 + (size_t)l * 16;

  // 3-slot half rotation: slot s holds half H (=2*kstep+ks) with H%3==s.
  s16x8 wH[3][2];
#pragma unroll
  for (int q = 0; q < 2; ++q) wH[0][q] = *(const s16x8*)(wl + q * 2048);          // H=0
#pragma unroll
  for (int q = 0; q < 2; ++q) wH[1][q] = *(const s16x8*)(wl + q * 2048 + 1024);   // H=1

  // prologue: stage g=0 into buffer 0
  {
    size_t gbase = (size_t)(b * 16) * 262144;             // (b,g) plane, bytes
#pragma unroll
    for (int r = 0; r < 6; ++r) {
      int gy = y0 - 1 + r;
      if (gy >= 0 && gy < HH)
        gload_lds16(xtb + gbase + (size_t)gy * 4096 + srcoff,
                    lds + r * XS_ROW + lds_woff);
    }
  }
  __syncthreads();

  s16x8 bfr0[2][4];   // ks=0, double-buffered by tap parity
  s16x8 bfr1[4];      // ks=1, read just-in-time under h0 MFMAs

  for (int g2 = 0; g2 < 8; ++g2) {
    const char* wg = wl + (size_t)g2 * 589824;   // base of kstep 18*g2
#pragma unroll
    for (int gg = 0; gg < 2; ++gg) {
      char* xs_r = lds + gg * XS_BUF;
      char* xs_w = lds + (gg ^ 1) * XS_BUF;
#pragma unroll
      for (int tap = 0; tap < 9; ++tap) {
        const int X0 = 2 * (gg * 9 + tap);       // even half id (compile-time)
        const int dy = tap / 3 - 1, dxi = tap % 3;
        const int rb = wr * 2 + 1 + dy;

        if (tap == 0) {
          // first tap after barrier: read this tap's ks0 frags (exposed wait)
#pragma unroll
          for (int dr = 0; dr < 2; ++dr)
#pragma unroll
            for (int ph = 0; ph < 2; ++ph)
              bfr0[0][dr * 2 + ph] =
                  *(const s16x8*)(xs_r + (rb + dr) * XS_ROW + boffs[ph][dxi][0]);
        }

        // stage next g's xs early (tap 6) -> ~2.5 taps of latency cover
        if (tap == 6 && (gg == 0 || g2 < 7)) {
          __builtin_amdgcn_sched_barrier(0);
          size_t gbase = (size_t)(b * 16 + g2 * 2 + gg + 1) * 262144;
#pragma unroll
          for (int r = 0; r < 6; ++r) {
            int gy = y0 - 1 + r;
            if (gy >= 0 && gy < HH)
              gload_lds16(xtb + gbase + (size_t)gy * 4096 + srcoff,
                          xs_w + r * XS_ROW + lds_woff);
          }
          __builtin_amdgcn_sched_barrier(0);
        }

        // ks=1 fragments for THIS tap (consumed at h1, covered by h0 MFMAs)
#pragma unroll
        for (int dr = 0; dr < 2; ++dr)
#pragma unroll
          for (int ph = 0; ph < 2; ++ph)
            bfr1[dr * 2 + ph] =
                *(const s16x8*)(xs_r + (rb + dr) * XS_ROW + boffs[ph][dxi][1]);

        // ---- h0: k-slice 0; prefetch weight half X0+2 ----
        {
          const char* wp = wg + (size_t)((X0 + 2) >> 1) * 32768 + ((X0 + 2) & 1) * 1024;
#pragma unroll
          for (int q = 0; q < 2; ++q)
            wH[(X0 + 2) % 3][q] = *(const s16x8*)(wp + q * 2048);
          __builtin_amdgcn_s_setprio(1);
#pragma unroll
          for (int q = 0; q < 2; ++q)
#pragma unroll
            for (int n = 0; n < 4; ++n)
              acc[q][n] = __builtin_amdgcn_mfma_f32_32x32x16_bf16(
                  wH[X0 % 3][q], bfr0[tap & 1][n], acc[q][n], 0, 0, 0);
          __builtin_amdgcn_s_setprio(0);
        }

        // prefetch next tap's ks0 frags (consumed next tap h0, covered by h1)
        if (tap < 8) {
          const int dyn = (tap + 1) / 3 - 1, dxn = (tap + 1) % 3;
          const int rbn = wr * 2 + 1 + dyn;
#pragma unroll
          for (int dr = 0; dr < 2; ++dr)
#pragma unroll
            for (int ph = 0; ph < 2; ++ph)
              bfr0[(tap + 1) & 1][dr * 2 + ph] =
                  *(const s16x8*)(xs_r + (rbn + dr) * XS_ROW + boffs[ph][dxn][0]);
        }

        // ---- h1: k-slice 1; prefetch weight half X0+3 ----
        {
          const char* wp = wg + (size_t)((X0 + 3) >> 1) * 32768 + ((X0 + 3) & 1) * 1024;
#pragma unroll
          for (int q = 0; q < 2; ++q)
            wH[(X0 + 3) % 3][q] = *(const s16x8*)(wp + q * 2048);
          __builtin_amdgcn_s_setprio(1);
#pragma unroll
          for (int q = 0; q < 2; ++q)
#pragma unroll
            for (int n = 0; n < 4; ++n)
              acc[q][n] = __builtin_amdgcn_mfma_f32_32x32x16_bf16(
                  wH[(X0 + 1) % 3][q], bfr1[n], acc[q][n], 0, 0, 0);
          __builtin_amdgcn_s_setprio(0);
        }

        if (tap == 8 && (gg == 0 || g2 < 7)) {
          // counted drain: tap-8's 4 weight loads stay in flight; 12 issues
          // since the xs DMAs -> vmcnt(4) guarantees staging complete
          __builtin_amdgcn_sched_barrier(0);
          asm volatile("s_waitcnt vmcnt(4)" ::: "memory");
          __builtin_amdgcn_sched_barrier(0);
          __builtin_amdgcn_s_barrier();
          __builtin_amdgcn_sched_barrier(0);
        }
      }
    }
  }

  // ---- epilogue: demod scale + store ----
  // C/D 32x32: col = l&31, row = (reg&3) + 8*(reg>>2) + 4*(l>>5)
  int gy_base = y0 + wr * 2;
  int colbase = l & 31;
  int rowadd = 4 * (l >> 5);
#pragma unroll
  for (int q = 0; q < 2; ++q) {
#pragma unroll
    for (int reg = 0; reg < 16; ++reg) {
      int row = (reg & 3) + 8 * (reg >> 2) + rowadd;
      int oc = ocb * 128 + (wm * 2 + q) * 32 + row;
      float dm = demod[b * COUT + oc];
#pragma unroll
      for (int n = 0; n < 4; ++n) {
        int gy = gy_base + (n >> 1);
        int px = (n & 1) * 32 + colbase;
        out[((size_t)(b * COUT + oc)) * 4096 + gy * 64 + px] = acc[q][n][reg] * dm;
      }
    }
  }
}

// ---------------------------------------------------------------------------
extern "C" void kernel_launch(void* const* d_in, const int* in_sizes, int n_in,
                              void* d_out, int out_size, void* d_ws, size_t ws_size,
                              hipStream_t stream) {
  const float* input = (const float*)d_in[0];  // [8,512,64,64]
  const float* style = (const float*)d_in[1];  // [8,512]
  const float* wa    = (const float*)d_in[2];  // [512,512]
  const float* ba    = (const float*)d_in[3];  // [1,512]
  const float* wconv = (const float*)d_in[4];  // [512,512,3,3]
  float* out = (float*)d_out;

  float* smod  = (float*)d_ws;                    // 4096 f
  float* demod = smod + BB * CIN;                 // 4096 f
  float* wsq   = demod + BB * COUT;               // 262144 f
  ushort* wfrag = (ushort*)(wsq + (size_t)COUT * CIN);   // 2,359,296 us (4.5 MB)
  ushort* xt    = wfrag + (size_t)16 * 9 * 32 * 64 * 8;  // 16,777,216 us (32 MB)

  affine_kernel<<<BB * CIN / 4, 256, 0, stream>>>(style, wa, ba, smod);
  wsq_kernel<<<COUT * CIN / 256, 256, 0, stream>>>(wconv, wsq);
  demod_kernel<<<BB * COUT / 4, 256, 0, stream>>>(smod, wsq, demod);
  wpack_kernel<<<16 * 9 * 32 * 64 / 256, 256, 0, stream>>>(wconv, wfrag);
  premod_kernel<<<BB * 16 * 64 * 64 * 4 / 256, 256, 0, stream>>>(input, smod, xt);
  conv_mfma<<<BB * 4 * 16, 256, 0, stream>>>(xt, wfrag, demod, out);
}

// Round 9
// 152.836 us; speedup vs baseline: 1.0615x; 1.0220x over previous
//
#include <hip/hip_runtime.h>
#include <hip/hip_bf16.h>

#define BB 8
#define CIN 512
#define COUT 512
#define HH 64
#define WW 64

#define AFF_SCALE 0.044194173824159216f     // 1/sqrt(512)
#define CONV_SCALE 0.014731391274719736f    // 1/sqrt(4608)
#define CONV_SCALE2 (1.0f/4608.0f)

typedef short s16x8 __attribute__((ext_vector_type(8)));
typedef float f32x16 __attribute__((ext_vector_type(16)));

__device__ __forceinline__ unsigned short f2bf(float f) {
  __hip_bfloat16 h = __float2bfloat16(f);
  return *reinterpret_cast<unsigned short*>(&h);
}

// zero-register global->LDS DMA, 16B per lane; LDS dest = uniform base + lane*16
__device__ __forceinline__ void gload_lds16(const void* g, void* l) {
  __builtin_amdgcn_global_load_lds(
      (const __attribute__((address_space(1))) unsigned int*)g,
      (__attribute__((address_space(3))) unsigned int*)l, 16, 0, 0);
}

// ---------------------------------------------------------------------------
// smod[b*CIN+ic] = dot(style[b,:], w_affine[ic,:]) * AFF_SCALE + ba[ic]
// ---------------------------------------------------------------------------
__global__ __launch_bounds__(256) void affine_kernel(
    const float* __restrict__ style, const float* __restrict__ wa,
    const float* __restrict__ ba, float* __restrict__ smod) {
  int wid  = (blockIdx.x << 2) + (threadIdx.x >> 6);
  int lane = threadIdx.x & 63;
  int b  = wid >> 9;
  int ic = wid & 511;
  const float* s = style + b * CIN;
  const float* w = wa + (size_t)ic * CIN;
  float sum = 0.f;
#pragma unroll
  for (int k = 0; k < CIN / 64; ++k) sum += s[lane + 64 * k] * w[lane + 64 * k];
#pragma unroll
  for (int off = 32; off; off >>= 1) sum += __shfl_down(sum, off, 64);
  if (lane == 0) smod[wid] = sum * AFF_SCALE + ba[ic];
}

// ---------------------------------------------------------------------------
// wsq[oc*CIN+ic] = sum_k w_conv[oc,ic,k]^2
// ---------------------------------------------------------------------------
__global__ __launch_bounds__(256) void wsq_kernel(
    const float* __restrict__ wc, float* __restrict__ wsq) {
  int i = blockIdx.x * 256 + threadIdx.x;
  const float* p = wc + (size_t)i * 9;
  float s = 0.f;
#pragma unroll
  for (int k = 0; k < 9; ++k) { float v = p[k]; s += v * v; }
  wsq[i] = s;
}

// ---------------------------------------------------------------------------
// demod[b*COUT+oc] = rsqrt(CS2 * sum_ic smod^2 * wsq + eps) * CS
// ---------------------------------------------------------------------------
__global__ __launch_bounds__(256) void demod_kernel(
    const float* __restrict__ smod, const float* __restrict__ wsq,
    float* __restrict__ demod) {
  int wid  = (blockIdx.x << 2) + (threadIdx.x >> 6);
  int lane = threadIdx.x & 63;
  int b  = wid >> 9;
  int oc = wid & 511;
  const float* s = smod + b * CIN;
  const float* w = wsq + (size_t)oc * CIN;
  float sum = 0.f;
#pragma unroll
  for (int k = 0; k < CIN / 64; ++k) {
    float sv = s[lane + 64 * k];
    sum += sv * sv * w[lane + 64 * k];
  }
#pragma unroll
  for (int off = 32; off; off >>= 1) sum += __shfl_down(sum, off, 64);
  if (lane == 0) demod[wid] = rsqrtf(sum * CONV_SCALE2 + 1e-8f) * CONV_SCALE;
}

// ---------------------------------------------------------------------------
// premod: xt[b][g][y][x][ic32] bf16 = input[b][ic][y][x] * smod[b][ic]
// ---------------------------------------------------------------------------
__global__ __launch_bounds__(256) void premod_kernel(
    const float* __restrict__ xin, const float* __restrict__ smod,
    ushort* __restrict__ xt) {
  int n = blockIdx.x * 256 + threadIdx.x;   // < 2,097,152
  int kg = n & 3;
  int x  = (n >> 2) & 63;
  int y  = (n >> 8) & 63;
  int g  = (n >> 14) & 15;
  int b  = n >> 18;
  int ic0 = g * 32 + kg * 8;
  const float* sp = smod + b * CIN + ic0;
  const float* xp = xin + (((size_t)b * CIN + ic0) * HH + y) * WW + x;
  s16x8 o;
#pragma unroll
  for (int j = 0; j < 8; ++j) {
    float v = xp[(size_t)j * HH * WW] * sp[j];
    o[j] = (short)f2bf(v);
  }
  *(s16x8*)(xt + (size_t)n * 8) = o;
}

// ---------------------------------------------------------------------------
// wpack (32x32x16 A-fragment order):
//   wfrag[widx][mf][ks][l][8], element = wc[oc = mf*32 + (l&31)]
//                                          [ic = g*32 + ks*16 + 8*(l>>5) + j]
//                                          [kh][kw],  widx = g*9 + tap
// ---------------------------------------------------------------------------
__global__ __launch_bounds__(256) void wpack_kernel(
    const float* __restrict__ wc, ushort* __restrict__ wfrag) {
  int n = blockIdx.x * 256 + threadIdx.x;   // < 294,912 = 144*16*2*64
  int l    = n & 63;
  int ks   = (n >> 6) & 1;
  int mf   = (n >> 7) & 15;
  int widx = n >> 11;           // 0..143
  int g = widx / 9, tap = widx % 9;
  int kh = tap / 3, kw = tap - kh * 3;
  int oc  = mf * 32 + (l & 31);
  int ic0 = g * 32 + ks * 16 + 8 * (l >> 5);
  s16x8 o;
#pragma unroll
  for (int j = 0; j < 8; ++j) {
    float v = wc[((size_t)oc * CIN + ic0 + j) * 9 + kh * 3 + kw];
    o[j] = (short)f2bf(v);
  }
  *(s16x8*)(wfrag + (size_t)n * 8) = o;
}

// ---------------------------------------------------------------------------
// conv_mfma (R9): dx-major tap order with 3-slot row-register rotation
// (bA/bB/bC) -> LDS B-reads cut 72->48 per g per wave. Weight prefetch
// distance doubled to 4 halves via 4-slot ping-pong (wHa..wHd); slot pairs
// swap with g-parity (18 halves/g % 4 == 2), compile-time via gg unroll.
// Staging at pos5 (~1000 cyc cover); barrier drain = counted vmcnt(16).
// tap(pos): perm = {0,3,6,1,4,7,2,5,8}; consumption rows pos(dx,dyi) =
// xs rows wr*2+dyi, +1 at shift dx. All slot/row indices compile-time.
// ---------------------------------------------------------------------------
#define XS_ROW 4224                 // 66 cols * 4 kg * 16 B
#define XS_BUF (6 * XS_ROW)         // 25344 B per buffer

#define MFMA1(A_, B_, C_) __builtin_amdgcn_mfma_f32_32x32x16_bf16(A_, B_, C_, 0, 0, 0)

// one k-half: 8 MFMAs (2 m-frags x 4 n-frags), W_ = slot (2 q-frags)
#define MH(W_, SX, SY, kf) \
  __builtin_amdgcn_s_setprio(1); \
  acc[0][0] = MFMA1(W_[0], SX[0 + (kf)], acc[0][0]); \
  acc[1][0] = MFMA1(W_[1], SX[0 + (kf)], acc[1][0]); \
  acc[0][1] = MFMA1(W_[0], SX[2 + (kf)], acc[0][1]); \
  acc[1][1] = MFMA1(W_[1], SX[2 + (kf)], acc[1][1]); \
  acc[0][2] = MFMA1(W_[0], SY[0 + (kf)], acc[0][2]); \
  acc[1][2] = MFMA1(W_[1], SY[0 + (kf)], acc[1][2]); \
  acc[0][3] = MFMA1(W_[0], SY[2 + (kf)], acc[0][3]); \
  acc[1][3] = MFMA1(W_[1], SY[2 + (kf)], acc[1][3]); \
  __builtin_amdgcn_s_setprio(0);

// weight prefetch: slot W_ <- (position-offset POFF within current g, ks KS)
#define WPRE(W_, POFF, KS) \
  W_[0] = *(const s16x8*)(wg + (size_t)(POFF) * 32768 + (KS) * 1024); \
  W_[1] = *(const s16x8*)(wg + (size_t)(POFF) * 32768 + 2048 + (KS) * 1024);

// B-slot load: xs row wr*2+RR at x-shift DXI (4 frags: [ph*2+ks])
#define LOADSLOT(S, RR, DXI) \
  S[0] = *(const s16x8*)(xs_r + (wr2 + (RR)) * XS_ROW + addrV[0][DXI][0]); \
  S[1] = *(const s16x8*)(xs_r + (wr2 + (RR)) * XS_ROW + addrV[0][DXI][1]); \
  S[2] = *(const s16x8*)(xs_r + (wr2 + (RR)) * XS_ROW + addrV[1][DXI][0]); \
  S[3] = *(const s16x8*)(xs_r + (wr2 + (RR)) * XS_ROW + addrV[1][DXI][1]);

#define GBARRIER \
  __builtin_amdgcn_sched_barrier(0); \
  asm volatile("s_waitcnt vmcnt(16)" ::: "memory"); \
  __builtin_amdgcn_sched_barrier(0); \
  __builtin_amdgcn_s_barrier(); \
  __builtin_amdgcn_sched_barrier(0);

// positions: p0..p8; even p -> slots (E0,E1), odd p -> (O0,O1).
// WPRE offsets = perm[p+2] with perm={0,3,6,1,4,7,2,5,8,9,12}.
#define GBODY(GG, E0, E1, O0, O1, TAILC) \
{ \
  const char* xs_r = (const char*)lds + (GG) * XS_BUF; \
  char* xs_w = lds + ((GG) ^ 1) * XS_BUF; \
  const char* wg = wl + (size_t)(g2 * 18 + (GG) * 9) * 32768; \
  LOADSLOT(bA, 0, 0) LOADSLOT(bB, 1, 0) \
  /*p0*/ MH(E0, bA, bB, 0) WPRE(E0, 6, 0) LOADSLOT(bC, 2, 0) \
         MH(E1, bA, bB, 1) WPRE(E1, 6, 1) \
  /*p1*/ MH(O0, bB, bC, 0) WPRE(O0, 1, 0) LOADSLOT(bA, 3, 0) \
         MH(O1, bB, bC, 1) WPRE(O1, 1, 1) \
  /*p2*/ MH(E0, bC, bA, 0) WPRE(E0, 4, 0) LOADSLOT(bB, 0, 1) \
         MH(E1, bC, bA, 1) WPRE(E1, 4, 1) LOADSLOT(bC, 1, 1) \
  /*p3*/ MH(O0, bB, bC, 0) WPRE(O0, 7, 0) LOADSLOT(bA, 2, 1) \
         MH(O1, bB, bC, 1) WPRE(O1, 7, 1) \
  /*p4*/ MH(E0, bC, bA, 0) WPRE(E0, 2, 0) LOADSLOT(bB, 3, 1) \
         MH(E1, bC, bA, 1) WPRE(E1, 2, 1) \
  /*p5*/ if (TAILC) stage6(xtb, (size_t)(b * 16 + g2 * 2 + (GG) + 1) * 262144, srcoff, xs_w, lds_woff, y0); \
         MH(O0, bA, bB, 0) WPRE(O0, 5, 0) LOADSLOT(bC, 0, 2) \
         MH(O1, bA, bB, 1) WPRE(O1, 5, 1) LOADSLOT(bA, 1, 2) \
  /*p6*/ MH(E0, bC, bA, 0) WPRE(E0, 8, 0) LOADSLOT(bB, 2, 2) \
         MH(E1, bC, bA, 1) WPRE(E1, 8, 1) \
  /*p7*/ MH(O0, bA, bB, 0) WPRE(O0, 9, 0) LOADSLOT(bC, 3, 2) \
         MH(O1, bA, bB, 1) WPRE(O1, 9, 1) \
  /*p8*/ MH(E0, bB, bC, 0) WPRE(E0, 12, 0) \
         MH(E1, bB, bC, 1) WPRE(E1, 12, 1) \
  if (TAILC) { GBARRIER } \
}

__device__ __forceinline__ void stage6(const char* xtb, size_t gbase, int srcoff,
                                       char* xs_w, int lds_woff, int y0) {
  __builtin_amdgcn_sched_barrier(0);
#pragma unroll
  for (int r = 0; r < 6; ++r) {
    int gy = y0 - 1 + r;
    if (gy >= 0 && gy < HH)
      gload_lds16(xtb + gbase + (size_t)gy * 4096 + srcoff,
                  xs_w + r * XS_ROW + lds_woff);
  }
  __builtin_amdgcn_sched_barrier(0);
}

__global__ __launch_bounds__(256, 2) void conv_mfma(
    const ushort* __restrict__ xt,     // [8][16][64][64][32] bf16
    const ushort* __restrict__ wfrag,  // [144][16][2][64][8] bf16
    const float* __restrict__ demod,
    float* __restrict__ out) {
  __shared__ char lds[2 * XS_BUF];    // 50688 B -> 2 blocks/CU

  int tid = threadIdx.x;
  int l = tid & 63, w = tid >> 6;
  int wm = w >> 1, wr = w & 1;        // oc-half, row-pair
  int wr2 = wr * 2;
  int bid = blockIdx.x;
  int ocb = bid & 3;
  int b   = (bid >> 2) & 7;
  int yt  = bid >> 5;           // 0..15
  int y0  = yt * 4;

  f32x16 acc[2][4];
#pragma unroll
  for (int i = 0; i < 2; ++i)
#pragma unroll
    for (int j = 0; j < 4; ++j)
#pragma unroll
      for (int e = 0; e < 16; ++e) acc[i][j][e] = 0.f;

  // zero always-zero halo COLUMNS (col 0 -> chunks 0..3, col 65 -> 260..263)
  if (tid < 96) {
    int buf = tid & 1, side = (tid >> 1) & 1, kgz = (tid >> 2) & 3, r = tid >> 4;
    int chunk = side ? (260 + kgz) : kgz;
    *(int4*)(lds + buf * XS_BUF + r * XS_ROW + chunk * 16) = int4{0, 0, 0, 0};
  }
  // zero y-halo ROWS for edge blocks (never re-staged -> stay zero)
  if (y0 == 0) {
    for (int i = tid; i < 512; i += 256) {
      int buf = i & 1, chunk = 4 + (i >> 1);
      *(int4*)(lds + buf * XS_BUF + chunk * 16) = int4{0, 0, 0, 0};
    }
  }
  if (y0 == 60) {
    for (int i = tid; i < 512; i += 256) {
      int buf = i & 1, chunk = 4 + (i >> 1);
      *(int4*)(lds + buf * XS_BUF + 5 * XS_ROW + chunk * 16) = int4{0, 0, 0, 0};
    }
  }

  // B-fragment read offsets (swizzled): col = ph*32 + (l&31) + dxi,
  // kg = (l>>5) + 2*ks;  addr = (col*4 + (kg ^ ((col>>1)&3))) * 16
  int addrV[2][3][2];
  {
    int lm = l & 31, kh2 = l >> 5;
#pragma unroll
    for (int ph = 0; ph < 2; ++ph)
#pragma unroll
      for (int dxi = 0; dxi < 3; ++dxi)
#pragma unroll
        for (int ks = 0; ks < 2; ++ks) {
          int col = ph * 32 + lm + dxi;                    // 0..65
          int kg  = kh2 + 2 * ks;
          addrV[ph][dxi][ks] = (col * 4 + (kg ^ ((col >> 1) & 3))) * 16;
        }
  }

  // staging: wave w covers quarter q=w of each row; per-lane PRE-SWIZZLED
  // global source offset within a 4KB xt row
  int col_s = 1 + w * 16 + (l >> 2);
  int srcoff = (col_s - 1) * 64 + ((l & 3) ^ ((col_s >> 1) & 3)) * 16;
  int lds_woff = 64 + w * 1024;   // + r*XS_ROW (+buf*XS_BUF)

  const char* xtb = (const char*)xt;
  // per-lane weight base for this wave's 2 m-frags:
  //   frag q (0..1), ks at  wl + kstep*32768 + q*2048 + ks*1024
  const char* wl = (const char*)wfrag + (size_t)(ocb * 4 + wm * 2) * 2048 + (size_t)l * 16;

  // prologue weight loads: halves c0..c3 = (p0,ks0/1), (p1=tap3,ks0/1)
  s16x8 wHa[2], wHb[2], wHc[2], wHd[2];
  wHa[0] = *(const s16x8*)(wl);                       wHa[1] = *(const s16x8*)(wl + 2048);
  wHb[0] = *(const s16x8*)(wl + 1024);                wHb[1] = *(const s16x8*)(wl + 3072);
  wHc[0] = *(const s16x8*)(wl + 3 * 32768);           wHc[1] = *(const s16x8*)(wl + 3 * 32768 + 2048);
  wHd[0] = *(const s16x8*)(wl + 3 * 32768 + 1024);    wHd[1] = *(const s16x8*)(wl + 3 * 32768 + 3072);

  // prologue: stage g=0 into buffer 0
  {
    size_t gbase = (size_t)(b * 16) * 262144;
#pragma unroll
    for (int r = 0; r < 6; ++r) {
      int gy = y0 - 1 + r;
      if (gy >= 0 && gy < HH)
        gload_lds16(xtb + gbase + (size_t)gy * 4096 + srcoff,
                    lds + r * XS_ROW + lds_woff);
    }
  }
  __syncthreads();

  s16x8 bA[4], bB[4], bC[4];

  for (int g2 = 0; g2 < 8; ++g2) {
    GBODY(0, wHa, wHb, wHc, wHd, true)
    GBODY(1, wHc, wHd, wHa, wHb, (g2 < 7))
  }

  // ---- epilogue: demod scale + store ----
  // C/D 32x32: col = l&31, row = (reg&3) + 8*(reg>>2) + 4*(l>>5)
  int gy_base = y0 + wr2;
  int colbase = l & 31;
  int rowadd = 4 * (l >> 5);
#pragma unroll
  for (int q = 0; q < 2; ++q) {
#pragma unroll
    for (int reg = 0; reg < 16; ++reg) {
      int row = (reg & 3) + 8 * (reg >> 2) + rowadd;
      int oc = ocb * 128 + (wm * 2 + q) * 32 + row;
      float dm = demod[b * COUT + oc];
#pragma unroll
      for (int n = 0; n < 4; ++n) {
        int gy = gy_base + (n >> 1);
        int px = (n & 1) * 32 + colbase;
        out[((size_t)(b * COUT + oc)) * 4096 + gy * 64 + px] = acc[q][n][reg] * dm;
      }
    }
  }
}

// ---------------------------------------------------------------------------
extern "C" void kernel_launch(void* const* d_in, const int* in_sizes, int n_in,
                              void* d_out, int out_size, void* d_ws, size_t ws_size,
                              hipStream_t stream) {
  const float* input = (const float*)d_in[0];  // [8,512,64,64]
  const float* style = (const float*)d_in[1];  // [8,512]
  const float* wa    = (const float*)d_in[2];  // [512,512]
  const float* ba    = (const float*)d_in[3];  // [1,512]
  const float* wconv = (const float*)d_in[4];  // [512,512,3,3]
  float* out = (float*)d_out;

  float* smod  = (float*)d_ws;                    // 4096 f
  float* demod = smod + BB * CIN;                 // 4096 f
  float* wsq   = demod + BB * COUT;               // 262144 f
  ushort* wfrag = (ushort*)(wsq + (size_t)COUT * CIN);   // 2,359,296 us (4.5 MB)
  ushort* xt    = wfrag + (size_t)16 * 9 * 32 * 64 * 8;  // 16,777,216 us (32 MB)

  affine_kernel<<<BB * CIN / 4, 256, 0, stream>>>(style, wa, ba, smod);
  wsq_kernel<<<COUT * CIN / 256, 256, 0, stream>>>(wconv, wsq);
  demod_kernel<<<BB * COUT / 4, 256, 0, stream>>>(smod, wsq, demod);
  wpack_kernel<<<16 * 9 * 32 * 64 / 256, 256, 0, stream>>>(wconv, wfrag);
  premod_kernel<<<BB * 16 * 64 * 64 * 4 / 256, 256, 0, stream>>>(input, smod, xt);
  conv_mfma<<<BB * 4 * 16, 256, 0, stream>>>(xt, wfrag, demod, out);
}